// Round 12
// baseline (128.292 us; speedup 1.0000x reference)
//
#include <hip/hip_runtime.h>
#include <cstdint>

// Problem constants (fixed by reference)
#define NT 3200   // B*N
#define NN 100    // N
#define FD 10     // F_IN
#define DD 64     // D
#define NCOPY 32  // BN atomic sink replicas (contention spreading)

// ---------------- threefry2x32 (JAX PRNG), host+device ----------------
__host__ __device__ inline void tf2x32(uint32_t ks0, uint32_t ks1, uint32_t x0,
                                       uint32_t x1, uint32_t& o0, uint32_t& o1) {
  uint32_t ks2 = ks0 ^ ks1 ^ 0x1BD11BDAu;
  x0 += ks0; x1 += ks1;
#define TF_RND(r) { x0 += x1; x1 = (x1 << (r)) | (x1 >> (32 - (r))); x1 ^= x0; }
  TF_RND(13) TF_RND(15) TF_RND(26) TF_RND(6)
  x0 += ks1; x1 += ks2 + 1u;
  TF_RND(17) TF_RND(29) TF_RND(16) TF_RND(24)
  x0 += ks2; x1 += ks0 + 2u;
  TF_RND(13) TF_RND(15) TF_RND(26) TF_RND(6)
  x0 += ks0; x1 += ks1 + 3u;
  TF_RND(17) TF_RND(29) TF_RND(16) TF_RND(24)
  x0 += ks1; x1 += ks2 + 4u;
  TF_RND(13) TF_RND(15) TF_RND(26) TF_RND(6)
  x0 += ks2; x1 += ks0 + 5u;
#undef TF_RND
  o0 = x0; o1 = x1;
}

// JAX partitionable random_bits(32) for counter (0, cnt); uniform(1e-20,1); gumbel.
__device__ inline float gumbel_noise(uint32_t ka, uint32_t kb, uint32_t cnt) {
  uint32_t o0, o1;
  tf2x32(ka, kb, 0u, cnt, o0, o1);
  uint32_t bits = o0 ^ o1;
  float u = __uint_as_float((bits >> 9) | 0x3F800000u) - 1.0f;
  u = fmaxf(u, 1e-20f);
  return -logf(-logf(u));
}

// ---------------- K1: per-row prep (blocks 0..799) + static adj (800..839) ----
__global__ __launch_bounds__(256) void k_prep_adj(
    const float* __restrict__ x, const float* __restrict__ ne,
    const float* __restrict__ lW, const float* __restrict__ lb,
    const float* __restrict__ Ws, const float* __restrict__ bs,
    const float* __restrict__ as_, const float* __restrict__ Wd,
    const float* __restrict__ bd, const float* __restrict__ ad,
    float* __restrict__ h_s, float* __restrict__ h_d, float* __restrict__ nd,
    float* __restrict__ q_s, float* __restrict__ kk_s, float* __restrict__ q_d,
    float* __restrict__ kk_d, float* __restrict__ adjS,
    float* __restrict__ gstat, uint32_t k1a, uint32_t k1b) {
  __shared__ float sne[NN * 65];
  __shared__ float dnorm[NN];
  int tid = threadIdx.x, wid = tid >> 6, lane = tid & 63;
  int blk = blockIdx.x;
  if (blk < 800) {
    // wave-per-row prep: h_s, h_d, normalized dyn-emb, attention projections
    int i = blk * 4 + wid;
    const float* xr = x + i * FD;
    float hs = bs[lane], hd = bd[lane], ed = lb[lane];
#pragma unroll
    for (int f = 0; f < FD; ++f) {
      float xv = xr[f];
      hs = fmaf(xv, Ws[f * DD + lane], hs);
      hd = fmaf(xv, Wd[f * DD + lane], hd);
      ed = fmaf(xv, lW[f * DD + lane], ed);
    }
    h_s[i * DD + lane] = hs;
    h_d[i * DD + lane] = hd;
    float ss = ed * ed;
    for (int off = 32; off > 0; off >>= 1) ss += __shfl_xor(ss, off, 64);
    nd[i * DD + lane] = ed / (sqrtf(ss) + 1e-8f);
    int r = i % NN;
    float em = ne[r * DD + lane];
    float ks = hs + em, kd = hd + em;
    float qs = ks * as_[lane], kks = ks * as_[DD + lane];
    float qd = kd * ad[lane], kkd = kd * ad[DD + lane];
    for (int off = 32; off > 0; off >>= 1) {
      qs += __shfl_xor(qs, off, 64);
      kks += __shfl_xor(kks, off, 64);
      qd += __shfl_xor(qd, off, 64);
      kkd += __shfl_xor(kkd, off, 64);
    }
    if (lane == 0) { q_s[i] = qs; kk_s[i] = kks; q_d[i] = qd; kk_d[i] = kkd; }
  } else {
    if (blk == 800) {  // zero all BN accumulator replicas
      for (int t = tid; t < NCOPY * 128; t += 256) gstat[t] = 0.0f;
    }
    // static adjacency: stage+normalize node_emb in LDS, 100x100 decisions
    {
      const float4* nev = (const float4*)ne;
      for (int idx = tid; idx < NN * DD / 4; idx += 256) {
        float4 v = nev[idx];
        int row = idx >> 4, c4 = (idx & 15) * 4;
        float* dst = &sne[row * 65 + c4];
        dst[0] = v.x; dst[1] = v.y; dst[2] = v.z; dst[3] = v.w;
      }
    }
    __syncthreads();
    for (int row = wid; row < NN; row += 4) {
      float v = sne[row * 65 + lane];
      float ss = v * v;
      for (int off = 32; off > 0; off >>= 1) ss += __shfl_xor(ss, off, 64);
      if (lane == 0) dnorm[row] = sqrtf(ss) + 1e-8f;
    }
    __syncthreads();
    for (int idx = tid; idx < NN * DD; idx += 256) {
      int row = idx >> 6;
      sne[row * 65 + (idx & 63)] /= dnorm[row];
    }
    __syncthreads();
    int p = (blk - 800) * 256 + tid;
    if (p < NN * NN) {
      int r = p / NN, c = p - r * NN;
      float sim = 0.0f;
#pragma unroll
      for (int k = 0; k < DD; ++k)
        sim = fmaf(sne[r * 65 + k], sne[c * 65 + k], sim);
      float g0 = gumbel_noise(k1a, k1b, (uint32_t)(2 * p));
      float g1 = gumbel_noise(k1a, k1b, (uint32_t)(2 * p + 1));
      bool edge = (sim + g0 >= 1.0f - sim + g1) || (r == c);
      adjS[p] = edge ? 1.0f : 0.0f;
    }
  }
}

// ---------------- K2: wave-per-row attention (high occupancy: 29.7KB LDS) ----
__global__ __launch_bounds__(256) void k_attn(
    const float* __restrict__ h_s, const float* __restrict__ h_d,
    const float* __restrict__ nd, const float* __restrict__ q_s,
    const float* __restrict__ kk_s, const float* __restrict__ q_d,
    const float* __restrict__ kk_d, const float* __restrict__ adjS,
    const float* __restrict__ ne, float* __restrict__ o,
    float* __restrict__ gstat, uint32_t k2a, uint32_t k2b) {
  __shared__ float lnd[NN * 65];   // pad 65 -> conflict-free row access
  __shared__ float att[4][2][NN];  // per-wave attention rows; reused for stats
  int tid = threadIdx.x, wid = tid >> 6, lane = tid & 63;
  int blk = blockIdx.x;
  int b = blk / 25, rb = (blk % 25) * 4;
  int base = b * NN;
  // stage normalized dynamic embeddings (float4 global loads, scalar LDS writes)
  {
    const float4* ndv = (const float4*)(nd + base * DD);
    for (int idx = tid; idx < NN * DD / 4; idx += 256) {
      float4 v = ndv[idx];
      int row = idx >> 4, c4 = (idx & 15) * 4;
      float* dst = &lnd[row * 65 + c4];
      dst[0] = v.x; dst[1] = v.y; dst[2] = v.z; dst[3] = v.w;
    }
  }
  __syncthreads();

  int r = rb + wid;
  int i = base + r;  // == blk*4 + wid
  float sqs = q_s[i], sqd = q_d[i];
  int j0 = lane, j1 = lane + 64;
  bool v1 = (j1 < NN);
  int jj1 = v1 ? j1 : 0;
  // cosine sims vs row r (LDS: broadcast + stride-65)
  float sim0 = 0.0f, sim1 = 0.0f;
  const float* ndr = &lnd[r * 65];
  const float* nj0 = &lnd[j0 * 65];
  const float* nj1 = &lnd[jj1 * 65];
#pragma unroll
  for (int k = 0; k < DD; ++k) {
    float a = ndr[k];
    sim0 = fmaf(a, nj0[k], sim0);
    sim1 = fmaf(a, nj1[k], sim1);
  }
  // static edges (precomputed adjacency)
  float es0 = -9e15f, es1 = -9e15f, ed0 = -9e15f, ed1 = -9e15f;
  if (adjS[r * NN + j0] > 0.0f) {
    float v = sqs + kk_s[base + j0];
    es0 = (v >= 0.0f) ? v : 0.2f * v;
  }
  if (v1 && adjS[r * NN + j1] > 0.0f) {
    float v = sqs + kk_s[base + j1];
    es1 = (v >= 0.0f) ? v : 0.2f * v;
  }
  // dynamic edges (gumbel on the fly)
  {
    uint32_t c0 = ((uint32_t)i * 3200u + (uint32_t)(base + j0)) * 2u;
    float g0 = gumbel_noise(k2a, k2b, c0);
    float g1 = gumbel_noise(k2a, k2b, c0 + 1u);
    if (sim0 + g0 >= 1.0f - sim0 + g1) {
      float v = sqd + kk_d[base + j0];
      ed0 = (v >= 0.0f) ? v : 0.2f * v;
    }
  }
  if (v1) {
    uint32_t c1 = ((uint32_t)i * 3200u + (uint32_t)(base + j1)) * 2u;
    float g0 = gumbel_noise(k2a, k2b, c1);
    float g1 = gumbel_noise(k2a, k2b, c1 + 1u);
    if (sim1 + g0 >= 1.0f - sim1 + g1) {
      float v = sqd + kk_d[base + j1];
      ed1 = (v >= 0.0f) ? v : 0.2f * v;
    }
  }
  // wave softmax, static (registers only)
  float ms = fmaxf(es0, es1);
  for (int off = 32; off > 0; off >>= 1) ms = fmaxf(ms, __shfl_xor(ms, off, 64));
  float ws0 = expf(es0 - ms);
  float ws1 = v1 ? expf(es1 - ms) : 0.0f;
  float Ss = ws0 + ws1;
  for (int off = 32; off > 0; off >>= 1) Ss += __shfl_xor(Ss, off, 64);
  att[wid][0][j0] = ws0 / Ss;
  if (v1) att[wid][0][j1] = ws1 / Ss;
  // wave softmax, dynamic
  float md = fmaxf(ed0, ed1);
  for (int off = 32; off > 0; off >>= 1) md = fmaxf(md, __shfl_xor(md, off, 64));
  float wd0 = expf(ed0 - md);
  float wd1 = v1 ? expf(ed1 - md) : 0.0f;
  float Sd = wd0 + wd1;
  for (int off = 32; off > 0; off >>= 1) Sd += __shfl_xor(Sd, off, 64);
  att[wid][1][j0] = wd0 / Sd;
  if (v1) att[wid][1][j1] = wd1 / Sd;
  // PV: lane = channel; att via wave-uniform LDS broadcast, h rows coalesced
  // from L2 (5 blocks/CU provides the TLP to hide L2 latency).
  float hs = 0.0f, hd2 = 0.0f;
  const float* hsp = h_s + base * DD + lane;
  const float* hdp = h_d + base * DD + lane;
#pragma unroll 4
  for (int j = 0; j < NN; ++j) {
    hs = fmaf(att[wid][0][j], hsp[j * DD], hs);
    hd2 = fmaf(att[wid][1][j], hdp[j * DD], hd2);
  }
  float eS = (hs > 0.0f) ? hs : expm1f(hs);
  float eD = (hd2 > 0.0f) ? hd2 : expm1f(hd2);
  float ov = (eS + 0.01f * eD) * ne[r * DD + lane];
  o[i * DD + lane] = ov;
  // BN partials: block reduce (reuse att), atomics into blk&31 replica
  __syncthreads();
  att[wid][0][lane] = ov;
  att[wid][1][lane] = ov * ov;
  __syncthreads();
  float* gs = gstat + (blk & (NCOPY - 1)) * 128;
  if (wid == 0) {
    float s = att[0][0][lane] + att[1][0][lane] + att[2][0][lane] + att[3][0][lane];
    unsafeAtomicAdd(&gs[lane], s);
  } else if (wid == 1) {
    float s = att[0][1][lane] + att[1][1][lane] + att[2][1][lane] + att[3][1][lane];
    unsafeAtomicAdd(&gs[64 + lane], s);
  }
}

// ---------------- K3: BN finalize + apply + ReLU + out projection ----------------
__global__ __launch_bounds__(256) void k_final(
    const float* __restrict__ o, const float* __restrict__ gstat,
    const float* __restrict__ gamma, const float* __restrict__ beta,
    const float* __restrict__ outW, const float* __restrict__ outb,
    float* __restrict__ out) {
  int tid = threadIdx.x, wid = tid >> 6, lane = tid & 63;
  int i = blockIdx.x * 4 + wid;
  float sm = 0.0f, s2 = 0.0f;
#pragma unroll
  for (int c = 0; c < NCOPY; ++c) {
    sm += gstat[c * 128 + lane];
    s2 += gstat[c * 128 + 64 + lane];
  }
  float m = sm * (1.0f / NT);
  float ex2 = s2 * (1.0f / NT);
  float var = ex2 - m * m;
  float scale = gamma[lane] / sqrtf(var + 1e-5f);
  float xv = o[i * DD + lane];
  float v = (xv - m) * scale + beta[lane];
  v = fmaxf(v, 0.0f);
  float p = v * outW[lane];
  for (int off = 32; off > 0; off >>= 1) p += __shfl_xor(p, off, 64);
  if (lane == 0) out[i] = p + outb[0];
}

extern "C" void kernel_launch(void* const* d_in, const int* in_sizes, int n_in,
                              void* d_out, int out_size, void* d_ws,
                              size_t ws_size, hipStream_t stream) {
  const float* data = (const float*)d_in[0];
  const float* node_emb = (const float*)d_in[1];
  const float* lin_W = (const float*)d_in[2];
  const float* lin_b = (const float*)d_in[3];
  const float* gat_s_W = (const float*)d_in[4];
  const float* gat_s_b = (const float*)d_in[5];
  const float* gat_s_a = (const float*)d_in[6];
  const float* gat_d_W = (const float*)d_in[7];
  const float* gat_d_b = (const float*)d_in[8];
  const float* gat_d_a = (const float*)d_in[9];
  const float* bn_gamma = (const float*)d_in[10];
  const float* bn_beta = (const float*)d_in[11];
  const float* out_W = (const float*)d_in[12];
  const float* out_b = (const float*)d_in[13];
  float* out = (float*)d_out;

  float* ws = (float*)d_ws;
  float* h_s = ws;                 // NT*DD
  float* h_d = ws + 204800;        // NT*DD
  float* nd = ws + 409600;         // NT*DD
  float* q_s = ws + 614400;        // NT
  float* kk_s = ws + 617600;       // NT
  float* q_d = ws + 620800;        // NT
  float* kk_d = ws + 624000;       // NT
  float* adjS = ws + 627200;       // NN*NN
  float* o = ws + 637200;          // NT*DD
  float* gstat = ws + 842000;      // NCOPY*128 (sum[64], sumsq[64] per copy)

  // JAX key(42): partitionable split -> k1=cipher(key,(0,0)), k2=cipher(key,(0,1))
  uint32_t k1a, k1b, k2a, k2b;
  tf2x32(0u, 42u, 0u, 0u, k1a, k1b);
  tf2x32(0u, 42u, 0u, 1u, k2a, k2b);

  k_prep_adj<<<840, 256, 0, stream>>>(data, node_emb, lin_W, lin_b, gat_s_W,
                                      gat_s_b, gat_s_a, gat_d_W, gat_d_b,
                                      gat_d_a, h_s, h_d, nd, q_s, kk_s, q_d,
                                      kk_d, adjS, gstat, k1a, k1b);
  k_attn<<<800, 256, 0, stream>>>(h_s, h_d, nd, q_s, kk_s, q_d, kk_d, adjS,
                                  node_emb, o, gstat, k2a, k2b);
  k_final<<<800, 256, 0, stream>>>(o, gstat, bn_gamma, bn_beta, out_W, out_b,
                                   out);
}